// Round 2
// baseline (154.226 us; speedup 1.0000x reference)
//
#include <hip/hip_runtime.h>
#include <hip/hip_bf16.h>

// CapsuleConv2d fused kernel, MI355X gfx950. ALL I/O IS FP32 (per reference).
// B=2, C_in=128 (G=8 groups x M=16), H=W=32, k=3x3 pad 1 -> OH=OW=32,
// O=16 out-capsules x L=16 -> C_out=256. k-means (dot) routing, 3 iters, squash.
// Layout: 1 block per (b,h,w) pixel; thread t = o*16+l; u[n=g*9+ij] in regs.
// Routing reductions over l use __shfl_xor within 16-lane groups (wave64-safe).

#define NPRI 72  // G(8) * KH*KW(9)

// Wt[ij][t][m] = W[o,l,m,i,j], t = o*16+l, flat = (ij*256 + t)*16 + m
__global__ void transpose_w_kernel(const float* __restrict__ W,
                                   float* __restrict__ Wt) {
    int idx = blockIdx.x * blockDim.x + threadIdx.x;  // 0..36863
    if (idx >= 9 * 256 * 16) return;
    int ij = idx >> 12;        // /4096
    int r  = idx & 4095;
    int t  = r >> 4;
    int m  = r & 15;
    Wt[idx] = W[(t * 16 + m) * 9 + ij];
}

template <bool USE_WT>
__global__ __launch_bounds__(256)
void capsule_kernel(const float* __restrict__ x,
                    const float* __restrict__ Wt,
                    const float* __restrict__ Wraw,
                    float* __restrict__ out) {
    __shared__ float patch[9 * 128];  // [ij][c], 4.6 KB

    const int blk = blockIdx.x;       // 2048 = 2*32*32
    const int b = blk >> 10;
    const int h = (blk >> 5) & 31;
    const int w = blk & 31;
    const int t = threadIdx.x;        // t = o*16 + l

    // ---- stage patch: x[b, c, h+di-1, w+dj-1] -> patch[ij*128 + c] ----
    const float* xb = x + b * (128 * 32 * 32);
    for (int idx = t; idx < 1152; idx += 256) {
        int c  = idx / 9;
        int ij = idx - c * 9;
        int di = ij / 3;
        int dj = ij - di * 3;
        int hh = h + di - 1;
        int ww = w + dj - 1;
        float v = 0.0f;
        if ((unsigned)hh < 32u && (unsigned)ww < 32u)
            v = xb[(c * 32 + hh) * 32 + ww];
        patch[ij * 128 + c] = v;
    }
    __syncthreads();

    // ---- priors: u[g*9+ij] = sum_m patch[ij][g*16+m] * W[t][m][ij] ----
    float u[NPRI];
    #pragma unroll
    for (int ij = 0; ij < 9; ++ij) {
        float wr[16];
        if (USE_WT) {
            const float* wp = Wt + (ij * 256 + t) * 16;  // 16 contiguous f32
            #pragma unroll
            for (int m = 0; m < 16; ++m) wr[m] = wp[m];
        } else {
            #pragma unroll
            for (int m = 0; m < 16; ++m)
                wr[m] = Wraw[(t * 16 + m) * 9 + ij];
        }
        #pragma unroll
        for (int g = 0; g < 8; ++g) {
            float acc = 0.0f;
            #pragma unroll
            for (int m = 0; m < 16; ++m)
                acc = fmaf(patch[ij * 128 + g * 16 + m], wr[m], acc);
            u[g * 9 + ij] = acc;
        }
    }

    // ---- k-means routing (dot similarity), 3 iterations ----
    // v init = mean over n
    float v = 0.0f;
    #pragma unroll
    for (int n = 0; n < NPRI; ++n) v += u[n];
    v *= (1.0f / NPRI);

    #pragma unroll 1
    for (int iter = 0; iter < 3; ++iter) {
        // ||v|| over l (16-lane group reduce)
        float s = v * v;
        s += __shfl_xor(s, 1);
        s += __shfl_xor(s, 2);
        s += __shfl_xor(s, 4);
        s += __shfl_xor(s, 8);
        float vn = v / fmaxf(sqrtf(s), 1e-12f);

        // fused: logit_n = sum_l u[n]*vn (group reduce), softmax over n
        // (no max-subtraction: |logit| <~ 5, exp safe in fp32), v = sum probs*u
        float ssum = 0.0f, vacc = 0.0f;
        #pragma unroll
        for (int n = 0; n < NPRI; ++n) {
            float p = u[n] * vn;
            p += __shfl_xor(p, 1);
            p += __shfl_xor(p, 2);
            p += __shfl_xor(p, 4);
            p += __shfl_xor(p, 8);
            float e = __expf(p);
            ssum += e;
            vacc = fmaf(e, u[n], vacc);
        }
        v = vacc / ssum;
    }

    // ---- squash: v * (||v|| / (1 + ||v||^2)) ----
    float s = v * v;
    s += __shfl_xor(s, 1);
    s += __shfl_xor(s, 2);
    s += __shfl_xor(s, 4);
    s += __shfl_xor(s, 8);
    float norm = sqrtf(s);
    float res  = v * (norm / (1.0f + s));

    // out[b, c=t, h, w]
    out[((b * 256 + t) * 32 + h) * 32 + w] = res;
}

extern "C" void kernel_launch(void* const* d_in, const int* in_sizes, int n_in,
                              void* d_out, int out_size, void* d_ws, size_t ws_size,
                              hipStream_t stream) {
    const float* x = (const float*)d_in[0];   // [2,128,32,32] fp32
    const float* W = (const float*)d_in[1];   // [16,16,16,3,3] fp32
    float* out = (float*)d_out;               // [2,256,32,32] fp32
    float* Wt = (float*)d_ws;

    if (ws_size >= (size_t)(9 * 256 * 16) * sizeof(float)) {
        transpose_w_kernel<<<144, 256, 0, stream>>>(W, Wt);
        capsule_kernel<true><<<2048, 256, 0, stream>>>(x, Wt, W, out);
    } else {
        capsule_kernel<false><<<2048, 256, 0, stream>>>(x, Wt, W, out);
    }
}

// Round 3
// 118.527 us; speedup vs baseline: 1.3012x; 1.3012x over previous
//
#include <hip/hip_runtime.h>

// CapsuleConv2d fused, MI355X gfx950. ALL I/O FP32.
// B=2, C_in=128 (G=8 x M=16), 32x32, 3x3 pad 1, O=16, L=16 -> C_out=256.
// k-means (dot) routing 3 iters + squash.
//
// Main kernel: 1 block per pixel, thread t=o*16+l, u[72] in VGPRs.
//  - patch read from global im2col buffer with wave-uniform addresses
//    -> s_load into SGPRs, FMA uses SGPR operand. NO LDS AT ALL.
//  - 16-lane reductions via DPP row_ror adds (VALU pipe, not LDS pipe).

#define NPRI 72
#define WT_ELEMS (9 * 256 * 16)          // 36864 floats = 147456 B
#define P_ELEMS  (2048 * 1152)           // 2359296 floats = 9437184 B

__device__ __forceinline__ float dpp_add16(float x) {
    // sum across each aligned 16-lane group; result broadcast to all 16 lanes.
    // rotate-reduce: ror 8, 4, 2, 1 within the DPP row (16 lanes on gfx9/CDNA).
    float s = x;
    s += __int_as_float(__builtin_amdgcn_update_dpp(
            0, __float_as_int(s), 0x128, 0xF, 0xF, true));  // row_ror:8
    s += __int_as_float(__builtin_amdgcn_update_dpp(
            0, __float_as_int(s), 0x124, 0xF, 0xF, true));  // row_ror:4
    s += __int_as_float(__builtin_amdgcn_update_dpp(
            0, __float_as_int(s), 0x122, 0xF, 0xF, true));  // row_ror:2
    s += __int_as_float(__builtin_amdgcn_update_dpp(
            0, __float_as_int(s), 0x121, 0xF, 0xF, true));  // row_ror:1
    return s;
}

__device__ __forceinline__ float frcp(float x) {
    return __builtin_amdgcn_rcpf(x);
}

// k-means routing (3 iters, dot similarity) + squash. u[n] per thread (o,l).
__device__ __forceinline__ float routing_squash(float (&u)[NPRI]) {
    float v = 0.0f;
    #pragma unroll
    for (int n = 0; n < NPRI; ++n) v += u[n];
    v *= (1.0f / NPRI);

    #pragma unroll 1
    for (int iter = 0; iter < 3; ++iter) {
        float s  = dpp_add16(v * v);
        float vn = v * frcp(fmaxf(sqrtf(s), 1e-12f));
        float ssum = 0.0f, vacc = 0.0f;
        #pragma unroll
        for (int n = 0; n < NPRI; ++n) {
            float p = dpp_add16(u[n] * vn);   // logit, broadcast over l-group
            float e = __expf(p);              // |p| small; no max-sub needed
            ssum += e;
            vacc = fmaf(e, u[n], vacc);
        }
        v = vacc * frcp(ssum);
    }

    float s = dpp_add16(v * v);
    return v * sqrtf(s) * frcp(1.0f + s);     // squash
}

// ---- prep: transpose weights + im2col, fused in one launch ----
// blocks [0,144):    Wt[(ij*256+t)*16+m] = W[((t*16+m)*9)+ij]
// blocks [144,2192): P[pix*1152 + ij*128 + c] = x[b,c,h+di-1,w+dj-1] (0-pad)
__global__ __launch_bounds__(256)
void prep_kernel(const float* __restrict__ x, const float* __restrict__ W,
                 float* __restrict__ Wt, float* __restrict__ P) {
    int blk = blockIdx.x;
    int t = threadIdx.x;
    if (blk < 144) {
        int idx = blk * 256 + t;            // 0..36863
        int ij = idx >> 12;
        int r  = idx & 4095;
        int tt = r >> 4;
        int m  = r & 15;
        Wt[idx] = W[(tt * 16 + m) * 9 + ij];
    } else {
        int pix = blk - 144;                // 0..2047
        int b = pix >> 10;
        int h = (pix >> 5) & 31;
        int w = pix & 31;
        const float* xb = x + b * (128 * 32 * 32);
        float* Pp = P + pix * 1152;
        #pragma unroll
        for (int k = 0; k < 5; ++k) {
            int idx = t + k * 256;
            if (idx < 1152) {
                int ij = idx >> 7;          // 0..8
                int c  = idx & 127;
                int di = ij / 3, dj = ij - di * 3;
                int hh = h + di - 1, ww = w + dj - 1;
                float v = 0.0f;
                if ((unsigned)hh < 32u && (unsigned)ww < 32u)
                    v = xb[(c * 32 + hh) * 32 + ww];
                Pp[idx] = v;
            }
        }
    }
}

// ---- main kernel: no LDS, patch via scalar loads ----
__global__ __launch_bounds__(256, 1)
void capsule_s_kernel(const float* __restrict__ P,
                      const float* __restrict__ Wt,
                      float* __restrict__ out) {
    const int pix = blockIdx.x;             // 2048
    const int b = pix >> 10;
    const int h = (pix >> 5) & 31;
    const int w = pix & 31;
    const int t = threadIdx.x;              // t = o*16 + l

    const float* __restrict__ Pp = P + pix * 1152;   // wave-uniform base

    float u[NPRI];
    #pragma unroll
    for (int ij = 0; ij < 9; ++ij) {
        float wr[16];
        const float* wp = Wt + (ij * 256 + t) * 16;  // 16 contig f32 per thread
        #pragma unroll
        for (int m = 0; m < 16; ++m) wr[m] = wp[m];

        #pragma unroll
        for (int g = 0; g < 8; ++g) {
            const float* sp = Pp + ij * 128 + g * 16;  // uniform -> s_load
            float acc = 0.0f;
            #pragma unroll
            for (int m = 0; m < 16; ++m)
                acc = fmaf(sp[m], wr[m], acc);         // v_fmac: sgpr x vgpr
            u[g * 9 + ij] = acc;
        }
    }

    float res = routing_squash(u);
    out[((b * 256 + t) * 32 + h) * 32 + w] = res;
}

// ---- fallback (small ws): round-2 structure, spill-fixed, DPP reductions ----
template <bool USE_WT>
__global__ __launch_bounds__(256, 1)
void capsule_lds_kernel(const float* __restrict__ x,
                        const float* __restrict__ Wt,
                        const float* __restrict__ Wraw,
                        float* __restrict__ out) {
    __shared__ float patch[9 * 128];
    const int blk = blockIdx.x;
    const int b = blk >> 10;
    const int h = (blk >> 5) & 31;
    const int w = blk & 31;
    const int t = threadIdx.x;

    const float* xb = x + b * (128 * 32 * 32);
    for (int idx = t; idx < 1152; idx += 256) {
        int c  = idx / 9;
        int ij = idx - c * 9;
        int di = ij / 3, dj = ij - di * 3;
        int hh = h + di - 1, ww = w + dj - 1;
        float v = 0.0f;
        if ((unsigned)hh < 32u && (unsigned)ww < 32u)
            v = xb[(c * 32 + hh) * 32 + ww];
        patch[ij * 128 + c] = v;
    }
    __syncthreads();

    float u[NPRI];
    #pragma unroll
    for (int ij = 0; ij < 9; ++ij) {
        float wr[16];
        if (USE_WT) {
            const float* wp = Wt + (ij * 256 + t) * 16;
            #pragma unroll
            for (int m = 0; m < 16; ++m) wr[m] = wp[m];
        } else {
            #pragma unroll
            for (int m = 0; m < 16; ++m)
                wr[m] = Wraw[(t * 16 + m) * 9 + ij];
        }
        #pragma unroll
        for (int g = 0; g < 8; ++g) {
            float acc = 0.0f;
            #pragma unroll
            for (int m = 0; m < 16; ++m)
                acc = fmaf(patch[ij * 128 + g * 16 + m], wr[m], acc);
            u[g * 9 + ij] = acc;
        }
    }

    float res = routing_squash(u);
    out[((b * 256 + t) * 32 + h) * 32 + w] = res;
}

extern "C" void kernel_launch(void* const* d_in, const int* in_sizes, int n_in,
                              void* d_out, int out_size, void* d_ws, size_t ws_size,
                              hipStream_t stream) {
    const float* x = (const float*)d_in[0];   // [2,128,32,32]
    const float* W = (const float*)d_in[1];   // [16,16,16,3,3]
    float* out = (float*)d_out;               // [2,256,32,32]
    float* Wt = (float*)d_ws;
    float* P  = Wt + WT_ELEMS;

    const size_t need_full = (size_t)(WT_ELEMS + P_ELEMS) * sizeof(float);
    const size_t need_wt   = (size_t)WT_ELEMS * sizeof(float);

    if (ws_size >= need_full) {
        prep_kernel<<<144 + 2048, 256, 0, stream>>>(x, W, Wt, P);
        capsule_s_kernel<<<2048, 256, 0, stream>>>(P, Wt, out);
    } else if (ws_size >= need_wt) {
        prep_kernel<<<144, 256, 0, stream>>>(x, W, Wt, (float*)nullptr);
        capsule_lds_kernel<true><<<2048, 256, 0, stream>>>(x, Wt, W, out);
    } else {
        capsule_lds_kernel<false><<<2048, 256, 0, stream>>>(x, Wt, W, out);
    }
}